// Round 7
// baseline (188.670 us; speedup 1.0000x reference)
//
#include <hip/hip_runtime.h>

// LearnedGCN: out = softmax(relu(se @ te), axis=1) @ x @ W.T + b
// N=16384, RANK=10, F=64, fp32 in/out.
//
// R7 vs R6 (math identical: both matmuls on MFMA, 3-band hi/lo score comp):
//  * occupancy 2x: 16 rows/block, grid 1024/launch, launch_bounds(512,8)
//  * log2(e) folded into se-frags -> raw v_exp_f32 (exp2), no per-p mul
//  * P->bf16 via native __bf16 casts (compiler emits v_cvt_pk_bf16_f32)
//  * lsum via all-ones B-frag MFMA (off the VALU; kills epilogue shuffles)
//  * preps merged into one kernel: 4 dispatches total
// ws stays 1.625 MiB (R6 proved ws_size >= 2MiB is unsafe to exceed; R4's 3MiB OOB'd).

constexpr int N    = 16384;
constexpr int RANK = 10;
constexpr int F    = 64;
constexpr int NH   = N / 2;          // j per phase

typedef float f32x4 __attribute__((ext_vector_type(4)));
typedef short bf16x8 __attribute__((ext_vector_type(8)));

constexpr float LOG2E = 1.4426950408889634f;

static __device__ __forceinline__ float fexp2(float x) {
    float r;
    asm("v_exp_f32 %0, %1" : "=v"(r) : "v"(x));
    return r;
}
static __device__ __forceinline__ unsigned short bfbits(float f) {
    return __builtin_bit_cast(unsigned short, (__bf16)f);
}

// -------- merged prep: blocks [0,256) -> yfrag, [256,384) -> tefrag ----------
// yfrag[(jl*4 + t)*64 + lane] slot b = Y[(js0+jl)*32 + 16*(b>>2)+4*g+(b&3)][t*16+il]
// tefrag[lt*64 + lane] slot b: k=8g+b; bands (hi|hi|lo) of te over rank 10,
//   value at te[r][(jt0+lt)*16 + il]; k>=30 -> 0.
__global__ __launch_bounds__(256)
void prep(const float* __restrict__ x, const float* __restrict__ W,
          const float* __restrict__ te,
          uint4* __restrict__ yfrag, uint4* __restrict__ tefrag,
          int js0, int jt0)
{
    const int tid  = threadIdx.x;
    const int lane = tid & 63;
    const int g = lane >> 4, il = lane & 15;

    if (blockIdx.x < 256) {
        // ---- Y = X @ W.T for one 32-row js ----
        __shared__ float xs[32][68];
        const int jl = blockIdx.x;
        const int js = js0 + jl;
#pragma unroll
        for (int i = 0; i < 2; ++i) {
            const int fi = tid * 2 + i;
            const int r = fi >> 4, c4 = fi & 15;
            const float4 v = *reinterpret_cast<const float4*>(x + (size_t)(js * 32 + r) * F + c4 * 4);
            *reinterpret_cast<float4*>(&xs[r][c4 * 4]) = v;
        }
        __syncthreads();
        const int t = tid >> 6;
        const int f = t * 16 + il;
        float y[8];
#pragma unroll
        for (int b = 0; b < 8; ++b) y[b] = 0.f;
        const float* wr = W + f * F;
#pragma unroll
        for (int k4 = 0; k4 < F / 4; ++k4) {
            const float4 wv = *reinterpret_cast<const float4*>(wr + 4 * k4);
#pragma unroll
            for (int b = 0; b < 8; ++b) {
                const int row = 16 * (b >> 2) + 4 * g + (b & 3);
                const float4 xv = *reinterpret_cast<const float4*>(&xs[row][4 * k4]);
                y[b] = fmaf(xv.x, wv.x, y[b]);
                y[b] = fmaf(xv.y, wv.y, y[b]);
                y[b] = fmaf(xv.z, wv.z, y[b]);
                y[b] = fmaf(xv.w, wv.w, y[b]);
            }
        }
        union { unsigned short us[8]; uint4 v; } pk;
#pragma unroll
        for (int b = 0; b < 8; ++b) pk.us[b] = bfbits(y[b]);
        yfrag[(jl * 4 + t) * 64 + lane] = pk.v;
    } else {
        // ---- te^T A-frags, banded ----
        const int lt = (blockIdx.x - 256) * 4 + (tid >> 6);
        const int jt = jt0 + lt;
        union { unsigned short us[8]; uint4 v; } pk;
#pragma unroll
        for (int b = 0; b < 8; ++b) {
            const int k = 8 * g + b;
            unsigned short o = 0;
            if (k < 30) {
                const int band = (k < 10) ? 0 : (k < 20 ? 1 : 2);
                const int r = k - band * 10;
                const float v = te[r * N + jt * 16 + il];
                const __bf16 hb = (__bf16)v;
                o = (band == 2) ? bfbits(v - (float)hb)
                                : __builtin_bit_cast(unsigned short, hb);
            }
            pk.us[b] = o;
        }
        tefrag[lt * 64 + lane] = pk.v;
    }
}

// -------- main kernel (one j-half, 16 rows/block, 8 j-split waves) ----------
// phase 0: out <- raw fp32 partial agg; lsum_self[row] <- partial lsum.
// phase 1: out <- (out + partial) / (lsum_other + partial_lsum) + bias.
__global__ __launch_bounds__(512, 8)
void gcn_main(const float* __restrict__ se, const uint4* __restrict__ tefrag,
              const uint4* __restrict__ yfrag, const float* __restrict__ bias,
              float* __restrict__ out, float* __restrict__ lsum_self,
              const float* __restrict__ lsum_other, int phase) {
    const int tid  = threadIdx.x;
    const int lane = tid & 63;
    const int wave = tid >> 6;            // j-split 0..7 within this half
    const int g = lane >> 4, il = lane & 15;
    const int rowbase = blockIdx.x << 4;  // 16 rows per block

    // se^T B-frag: a = se*log2e, bands (hi|lo|hi) pairing te's (hi|hi|lo)
    bf16x8 sef;
    {
        union { unsigned short us[8]; bf16x8 v; } pk;
        const int row = rowbase + il;
#pragma unroll
        for (int b = 0; b < 8; ++b) {
            const int k = 8 * g + b;
            unsigned short o = 0;
            if (k < 30) {
                const int band = (k < 10) ? 0 : (k < 20 ? 1 : 2);
                const int r = k - band * 10;
                const float a = se[row * RANK + r] * LOG2E;
                const __bf16 hb = (__bf16)a;
                o = (band == 1) ? bfbits(a - (float)hb)
                                : __builtin_bit_cast(unsigned short, hb);
            }
            pk.us[b] = o;
        }
        sef = pk.v;
    }

    // all-ones B-frag for the lsum column (bf16 1.0 = 0x3F80)
    union { unsigned short us[8]; bf16x8 v; } onesu;
#pragma unroll
    for (int b = 0; b < 8; ++b) onesu.us[b] = 0x3F80;
    const bf16x8 ones = onesu.v;

    f32x4 acc[4];
#pragma unroll
    for (int ft = 0; ft < 4; ++ft) acc[ft] = f32x4{0.f, 0.f, 0.f, 0.f};
    f32x4 accL = {0.f, 0.f, 0.f, 0.f};

    // this wave's j-chunk: 1024 j = 32 K-steps of 32 j
    const uint4* tb = tefrag + (size_t)wave * 64 * 64 + lane;
    const uint4* yb = yfrag + (size_t)wave * 32 * 256 + lane;

    for (int s = 0; s < 32; ++s) {
        const uint4 ta0 = tb[0];
        const uint4 ta1 = tb[64];
        const uint4 y0 = yb[0];
        const uint4 y1 = yb[64];
        const uint4 y2 = yb[128];
        const uint4 y3 = yb[192];

        const f32x4 z = {0.f, 0.f, 0.f, 0.f};
        const f32x4 sc0 = __builtin_amdgcn_mfma_f32_16x16x32_bf16(__builtin_bit_cast(bf16x8, ta0), sef, z, 0, 0, 0);
        const f32x4 sc1 = __builtin_amdgcn_mfma_f32_16x16x32_bf16(__builtin_bit_cast(bf16x8, ta1), sef, z, 0, 0, 0);

        union { __bf16 h[8]; bf16x8 v; } af;
#pragma unroll
        for (int q = 0; q < 4; ++q) {
            const float p0 = fexp2(fmaxf(sc0[q], 0.f));
            const float p1 = fexp2(fmaxf(sc1[q], 0.f));
            af.h[q]     = (__bf16)p0;
            af.h[4 + q] = (__bf16)p1;
        }

        acc[0] = __builtin_amdgcn_mfma_f32_16x16x32_bf16(af.v, __builtin_bit_cast(bf16x8, y0), acc[0], 0, 0, 0);
        acc[1] = __builtin_amdgcn_mfma_f32_16x16x32_bf16(af.v, __builtin_bit_cast(bf16x8, y1), acc[1], 0, 0, 0);
        acc[2] = __builtin_amdgcn_mfma_f32_16x16x32_bf16(af.v, __builtin_bit_cast(bf16x8, y2), acc[2], 0, 0, 0);
        acc[3] = __builtin_amdgcn_mfma_f32_16x16x32_bf16(af.v, __builtin_bit_cast(bf16x8, y3), acc[3], 0, 0, 0);
        accL   = __builtin_amdgcn_mfma_f32_16x16x32_bf16(af.v, ones, accL, 0, 0, 0);

        tb += 128;
        yb += 256;
    }

    // ---- combine 8 wave-chunks ----
    __shared__ float s_acc[4][1024];   // [buf][row16*64 + feat]
    __shared__ float s_l[8][16];

    if (il == 0) {
#pragma unroll
        for (int q = 0; q < 4; ++q) s_l[wave][4 * g + q] = accL[q];
    }
    if (wave < 4) {
#pragma unroll
        for (int ft = 0; ft < 4; ++ft)
#pragma unroll
            for (int q = 0; q < 4; ++q)
                s_acc[wave][(4 * g + q) * 64 + ft * 16 + il] = acc[ft][q];
    }
    __syncthreads();
    if (wave >= 4) {
#pragma unroll
        for (int ft = 0; ft < 4; ++ft)
#pragma unroll
            for (int q = 0; q < 4; ++q)
                s_acc[wave - 4][(4 * g + q) * 64 + ft * 16 + il] += acc[ft][q];
    }
    __syncthreads();

    // epilogue: 256 threads x 4 floats = 1024 outputs (16 rows x 64 feats)
    if (tid < 256) {
        const int idx  = tid << 2;
        const int row  = idx >> 6;
        const int feat = idx & 63;
        f32x4 v = {0.f, 0.f, 0.f, 0.f};
#pragma unroll
        for (int w = 0; w < 4; ++w) v = v + *reinterpret_cast<const f32x4*>(&s_acc[w][idx]);
        float ls = 0.f;
#pragma unroll
        for (int w = 0; w < 8; ++w) ls += s_l[w][row];

        const int orow = rowbase + row;
        float* op = out + (size_t)orow * F + feat;

        if (phase == 0) {
            if (feat == 0) lsum_self[orow] = ls;
            float4 o; o.x = v[0]; o.y = v[1]; o.z = v[2]; o.w = v[3];
            *reinterpret_cast<float4*>(op) = o;
        } else {
            const float4 prev = *reinterpret_cast<const float4*>(op);
            const float inv = 1.f / (ls + lsum_other[orow]);
            const float4 bv = *reinterpret_cast<const float4*>(bias + feat);
            float4 o;
            o.x = (v[0] + prev.x) * inv + bv.x;
            o.y = (v[1] + prev.y) * inv + bv.y;
            o.z = (v[2] + prev.z) * inv + bv.z;
            o.w = (v[3] + prev.w) * inv + bv.w;
            *reinterpret_cast<float4*>(op) = o;
        }
    }
}

extern "C" void kernel_launch(void* const* d_in, const int* in_sizes, int n_in,
                              void* d_out, int out_size, void* d_ws, size_t ws_size,
                              hipStream_t stream) {
    const float* x  = (const float*)d_in[0];
    const float* se = (const float*)d_in[1];
    const float* te = (const float*)d_in[2];
    const float* W  = (const float*)d_in[3];
    const float* b  = (const float*)d_in[4];
    float* out = (float*)d_out;

    // ws layout (1.625 MiB total; ws_size proven >= 2MiB, < 3MiB):
    //   [0, 512K)        tefrag half  (512 tiles x 64 x 16B)
    //   [512K, 1.5M)     yfrag half   (256 js x 4 x 64 x 16B)
    //   [1.5M, +64K)     lsumA        [+64K, +128K) lsumB
    uint4* tefrag = (uint4*)d_ws;
    uint4* yfrag  = (uint4*)((char*)d_ws + (512u << 10));
    float* lsumA  = (float*)((char*)d_ws + (1536u << 10));
    float* lsumB  = lsumA + N;

    // phase A: j in [0, 8192)
    prep<<<384, 256, 0, stream>>>(x, W, te, yfrag, tefrag, 0, 0);
    gcn_main<<<N / 16, 512, 0, stream>>>(se, tefrag, yfrag, b, out, lsumA, lsumB, 0);

    // phase B: j in [8192, 16384)
    prep<<<384, 256, 0, stream>>>(x, W, te, yfrag, tefrag, NH / 32, NH / 16);
    gcn_main<<<N / 16, 512, 0, stream>>>(se, tefrag, yfrag, b, out, lsumB, lsumA, 1);
}

// Round 9
// 150.953 us; speedup vs baseline: 1.2499x; 1.2499x over previous
//
#include <hip/hip_runtime.h>

// LearnedGCN: out = softmax(relu(se @ te), axis=1) @ x @ W.T + b
// N=16384, RANK=10, F=64, fp32 in/out.
//
// R8 vs R7 (math identical: both matmuls on MFMA, 3-band hi/lo score comp,
// exp2 with log2e folded into se-frags, lsum via all-ones MFMA):
//  * 64 rows/block (4 row-tiles per wave) -> each ta/y fragment load is
//    amortized over 4x the output rows. Per-launch L2 fragment traffic
//    1.5GiB (R7) -> 384MiB. R7 regression was L2-BW-bound re-reads.
//  * grid 256 = 1 block/CU exactly -> VGPR up to 256 free; launch_bounds(512,2).
// ws stays 1.625 MiB (ws_size proven >= 2MiB and < 3MiB; R4's 3MiB OOB'd).

constexpr int N    = 16384;
constexpr int RANK = 10;
constexpr int F    = 64;
constexpr int NH   = N / 2;          // j per phase

typedef float f32x4 __attribute__((ext_vector_type(4)));
typedef short bf16x8 __attribute__((ext_vector_type(8)));

constexpr float LOG2E = 1.4426950408889634f;

static __device__ __forceinline__ float fexp2(float x) {
    float r;
    asm("v_exp_f32 %0, %1" : "=v"(r) : "v"(x));
    return r;
}
static __device__ __forceinline__ unsigned short bfbits(float f) {
    return __builtin_bit_cast(unsigned short, (__bf16)f);
}

// -------- merged prep: blocks [0,256) -> yfrag, [256,384) -> tefrag ----------
// yfrag[(jl*4 + t)*64 + lane] slot b = Y[(js0+jl)*32 + 16*(b>>2)+4*g+(b&3)][t*16+il]
// tefrag[lt*64 + lane] slot b: k=8g+b; bands (hi|hi|lo) of te over rank 10,
//   value at te[r][(jt0+lt)*16 + il]; k>=30 -> 0.
__global__ __launch_bounds__(256)
void prep(const float* __restrict__ x, const float* __restrict__ W,
          const float* __restrict__ te,
          uint4* __restrict__ yfrag, uint4* __restrict__ tefrag,
          int js0, int jt0)
{
    const int tid  = threadIdx.x;
    const int lane = tid & 63;
    const int g = lane >> 4, il = lane & 15;

    if (blockIdx.x < 256) {
        // ---- Y = X @ W.T for one 32-row js ----
        __shared__ float xs[32][68];
        const int jl = blockIdx.x;
        const int js = js0 + jl;
#pragma unroll
        for (int i = 0; i < 2; ++i) {
            const int fi = tid * 2 + i;
            const int r = fi >> 4, c4 = fi & 15;
            const float4 v = *reinterpret_cast<const float4*>(x + (size_t)(js * 32 + r) * F + c4 * 4);
            *reinterpret_cast<float4*>(&xs[r][c4 * 4]) = v;
        }
        __syncthreads();
        const int t = tid >> 6;
        const int f = t * 16 + il;
        float y[8];
#pragma unroll
        for (int b = 0; b < 8; ++b) y[b] = 0.f;
        const float* wr = W + f * F;
#pragma unroll
        for (int k4 = 0; k4 < F / 4; ++k4) {
            const float4 wv = *reinterpret_cast<const float4*>(wr + 4 * k4);
#pragma unroll
            for (int b = 0; b < 8; ++b) {
                const int row = 16 * (b >> 2) + 4 * g + (b & 3);
                const float4 xv = *reinterpret_cast<const float4*>(&xs[row][4 * k4]);
                y[b] = fmaf(xv.x, wv.x, y[b]);
                y[b] = fmaf(xv.y, wv.y, y[b]);
                y[b] = fmaf(xv.z, wv.z, y[b]);
                y[b] = fmaf(xv.w, wv.w, y[b]);
            }
        }
        union { unsigned short us[8]; uint4 v; } pk;
#pragma unroll
        for (int b = 0; b < 8; ++b) pk.us[b] = bfbits(y[b]);
        yfrag[(jl * 4 + t) * 64 + lane] = pk.v;
    } else {
        // ---- te^T A-frags, banded ----
        const int lt = (blockIdx.x - 256) * 4 + (tid >> 6);
        const int jt = jt0 + lt;
        union { unsigned short us[8]; uint4 v; } pk;
#pragma unroll
        for (int b = 0; b < 8; ++b) {
            const int k = 8 * g + b;
            unsigned short o = 0;
            if (k < 30) {
                const int band = (k < 10) ? 0 : (k < 20 ? 1 : 2);
                const int r = k - band * 10;
                const float v = te[r * N + jt * 16 + il];
                const __bf16 hb = (__bf16)v;
                o = (band == 2) ? bfbits(v - (float)hb)
                                : __builtin_bit_cast(unsigned short, hb);
            }
            pk.us[b] = o;
        }
        tefrag[lt * 64 + lane] = pk.v;
    }
}

// -------- main kernel (one j-half, 64 rows/block, 8 j-split waves) ----------
// phase 0: out <- raw fp32 partial agg; lsum_self[row] <- partial lsum.
// phase 1: out <- (out + partial) / (lsum_other + partial_lsum) + bias.
__global__ __launch_bounds__(512, 2)
void gcn_main(const float* __restrict__ se, const uint4* __restrict__ tefrag,
              const uint4* __restrict__ yfrag, const float* __restrict__ bias,
              float* __restrict__ out, float* __restrict__ lsum_self,
              const float* __restrict__ lsum_other, int phase) {
    const int tid  = threadIdx.x;
    const int lane = tid & 63;
    const int wave = tid >> 6;            // j-split 0..7 within this half
    const int g = lane >> 4, il = lane & 15;
    const int rowbase = blockIdx.x << 6;  // 64 rows per block

    // se^T B-frags, 4 row-tiles: a = se*log2e, bands (hi|lo|hi) pairing
    // te's (hi|hi|lo)
    bf16x8 sef[4];
#pragma unroll
    for (int rt = 0; rt < 4; ++rt) {
        union { unsigned short us[8]; bf16x8 v; } pk;
        const int row = rowbase + rt * 16 + il;
#pragma unroll
        for (int b = 0; b < 8; ++b) {
            const int k = 8 * g + b;
            unsigned short o = 0;
            if (k < 30) {
                const int band = (k < 10) ? 0 : (k < 20 ? 1 : 2);
                const int r = k - band * 10;
                const float a = se[row * RANK + r] * LOG2E;
                const __bf16 hb = (__bf16)a;
                o = (band == 1) ? bfbits(a - (float)hb)
                                : __builtin_bit_cast(unsigned short, hb);
            }
            pk.us[b] = o;
        }
        sef[rt] = pk.v;
    }

    // all-ones B-frag for the lsum column (bf16 1.0 = 0x3F80)
    union { unsigned short us[8]; bf16x8 v; } onesu;
#pragma unroll
    for (int b = 0; b < 8; ++b) onesu.us[b] = 0x3F80;
    const bf16x8 ones = onesu.v;

    f32x4 acc[4][4];
#pragma unroll
    for (int rt = 0; rt < 4; ++rt)
#pragma unroll
        for (int ft = 0; ft < 4; ++ft) acc[rt][ft] = f32x4{0.f, 0.f, 0.f, 0.f};
    f32x4 accL[4];
#pragma unroll
    for (int rt = 0; rt < 4; ++rt) accL[rt] = f32x4{0.f, 0.f, 0.f, 0.f};

    // this wave's j-chunk: 1024 j = 32 K-steps of 32 j
    const uint4* tb = tefrag + (size_t)wave * 64 * 64 + lane;
    const uint4* yb = yfrag + (size_t)wave * 32 * 256 + lane;

    for (int s = 0; s < 32; ++s) {
        const uint4 ta0 = tb[0];
        const uint4 ta1 = tb[64];
        const uint4 y0 = yb[0];
        const uint4 y1 = yb[64];
        const uint4 y2 = yb[128];
        const uint4 y3 = yb[192];
        const f32x4 z = {0.f, 0.f, 0.f, 0.f};

#pragma unroll
        for (int rt = 0; rt < 4; ++rt) {
            const f32x4 sc0 = __builtin_amdgcn_mfma_f32_16x16x32_bf16(__builtin_bit_cast(bf16x8, ta0), sef[rt], z, 0, 0, 0);
            const f32x4 sc1 = __builtin_amdgcn_mfma_f32_16x16x32_bf16(__builtin_bit_cast(bf16x8, ta1), sef[rt], z, 0, 0, 0);

            union { __bf16 h[8]; bf16x8 v; } af;
#pragma unroll
            for (int q = 0; q < 4; ++q) {
                af.h[q]     = (__bf16)fexp2(fmaxf(sc0[q], 0.f));
                af.h[4 + q] = (__bf16)fexp2(fmaxf(sc1[q], 0.f));
            }

            acc[rt][0] = __builtin_amdgcn_mfma_f32_16x16x32_bf16(af.v, __builtin_bit_cast(bf16x8, y0), acc[rt][0], 0, 0, 0);
            acc[rt][1] = __builtin_amdgcn_mfma_f32_16x16x32_bf16(af.v, __builtin_bit_cast(bf16x8, y1), acc[rt][1], 0, 0, 0);
            acc[rt][2] = __builtin_amdgcn_mfma_f32_16x16x32_bf16(af.v, __builtin_bit_cast(bf16x8, y2), acc[rt][2], 0, 0, 0);
            acc[rt][3] = __builtin_amdgcn_mfma_f32_16x16x32_bf16(af.v, __builtin_bit_cast(bf16x8, y3), acc[rt][3], 0, 0, 0);
            accL[rt]   = __builtin_amdgcn_mfma_f32_16x16x32_bf16(af.v, ones, accL[rt], 0, 0, 0);
        }

        tb += 128;
        yb += 256;
    }

    // ---- combine 8 wave-chunks ----
    __shared__ float s_acc[4][4096];   // [buf][row64*64 + feat]  (64 KB)
    __shared__ float s_l[8][64];

    if (il == 0) {
#pragma unroll
        for (int rt = 0; rt < 4; ++rt)
#pragma unroll
            for (int q = 0; q < 4; ++q) s_l[wave][rt * 16 + 4 * g + q] = accL[rt][q];
    }
    if (wave < 4) {
#pragma unroll
        for (int rt = 0; rt < 4; ++rt)
#pragma unroll
            for (int ft = 0; ft < 4; ++ft)
#pragma unroll
                for (int q = 0; q < 4; ++q)
                    s_acc[wave][(rt * 16 + 4 * g + q) * 64 + ft * 16 + il] = acc[rt][ft][q];
    }
    __syncthreads();
    if (wave >= 4) {
#pragma unroll
        for (int rt = 0; rt < 4; ++rt)
#pragma unroll
            for (int ft = 0; ft < 4; ++ft)
#pragma unroll
                for (int q = 0; q < 4; ++q)
                    s_acc[wave - 4][(rt * 16 + 4 * g + q) * 64 + ft * 16 + il] += acc[rt][ft][q];
    }
    __syncthreads();

    // epilogue: 512 threads x 8 floats = 4096 outputs (64 rows x 64 feats)
    const int e    = tid << 3;
    const int row  = e >> 6;
    const int feat = e & 63;
    f32x4 v0 = {0.f, 0.f, 0.f, 0.f}, v1 = {0.f, 0.f, 0.f, 0.f};
#pragma unroll
    for (int w = 0; w < 4; ++w) {
        v0 = v0 + *reinterpret_cast<const f32x4*>(&s_acc[w][row * 64 + feat]);
        v1 = v1 + *reinterpret_cast<const f32x4*>(&s_acc[w][row * 64 + feat + 4]);
    }
    float ls = 0.f;
#pragma unroll
    for (int w = 0; w < 8; ++w) ls += s_l[w][row];

    const int orow = rowbase + row;
    float* op = out + (size_t)orow * F + feat;

    if (phase == 0) {
        if (feat == 0) lsum_self[orow] = ls;
        float4 o0, o1;
        o0.x = v0[0]; o0.y = v0[1]; o0.z = v0[2]; o0.w = v0[3];
        o1.x = v1[0]; o1.y = v1[1]; o1.z = v1[2]; o1.w = v1[3];
        *reinterpret_cast<float4*>(op)     = o0;
        *reinterpret_cast<float4*>(op + 4) = o1;
    } else {
        const float4 p0 = *reinterpret_cast<const float4*>(op);
        const float4 p1 = *reinterpret_cast<const float4*>(op + 4);
        const float inv = 1.f / (ls + lsum_other[orow]);
        const float4 b0 = *reinterpret_cast<const float4*>(bias + feat);
        const float4 b1 = *reinterpret_cast<const float4*>(bias + feat + 4);
        float4 o0, o1;
        o0.x = (v0[0] + p0.x) * inv + b0.x;
        o0.y = (v0[1] + p0.y) * inv + b0.y;
        o0.z = (v0[2] + p0.z) * inv + b0.z;
        o0.w = (v0[3] + p0.w) * inv + b0.w;
        o1.x = (v1[0] + p1.x) * inv + b1.x;
        o1.y = (v1[1] + p1.y) * inv + b1.y;
        o1.z = (v1[2] + p1.z) * inv + b1.z;
        o1.w = (v1[3] + p1.w) * inv + b1.w;
        *reinterpret_cast<float4*>(op)     = o0;
        *reinterpret_cast<float4*>(op + 4) = o1;
    }
}

extern "C" void kernel_launch(void* const* d_in, const int* in_sizes, int n_in,
                              void* d_out, int out_size, void* d_ws, size_t ws_size,
                              hipStream_t stream) {
    const float* x  = (const float*)d_in[0];
    const float* se = (const float*)d_in[1];
    const float* te = (const float*)d_in[2];
    const float* W  = (const float*)d_in[3];
    const float* b  = (const float*)d_in[4];
    float* out = (float*)d_out;

    // ws layout (1.625 MiB total; ws_size proven >= 2MiB, < 3MiB):
    //   [0, 512K)        tefrag half  (512 tiles x 64 x 16B)
    //   [512K, 1.5M)     yfrag half   (256 js x 4 x 64 x 16B)
    //   [1.5M, +64K)     lsumA        [+64K, +128K) lsumB
    uint4* tefrag = (uint4*)d_ws;
    uint4* yfrag  = (uint4*)((char*)d_ws + (512u << 10));
    float* lsumA  = (float*)((char*)d_ws + (1536u << 10));
    float* lsumB  = lsumA + N;

    // phase A: j in [0, 8192)
    prep<<<384, 256, 0, stream>>>(x, W, te, yfrag, tefrag, 0, 0);
    gcn_main<<<N / 64, 512, 0, stream>>>(se, tefrag, yfrag, b, out, lsumA, lsumB, 0);

    // phase B: j in [8192, 16384)
    prep<<<384, 256, 0, stream>>>(x, W, te, yfrag, tefrag, NH / 32, NH / 16);
    gcn_main<<<N / 64, 512, 0, stream>>>(se, tefrag, yfrag, b, out, lsumB, lsumA, 1);
}